// Round 7
// baseline (228.793 us; speedup 1.0000x reference)
//
#include <hip/hip_runtime.h>
#include <hip/hip_bf16.h>
#include <math.h>

// Problem constants
#define BT    96          // B*T = 8*12
#define NSEQ  512         // N
#define DMODEL 64         // D = K*d
#define RTOT  (BT * NSEQ) // 49152 rows

// Workspace layout (floats)
#define QOFF  0
#define KOFF  ((size_t)RTOT * DMODEL)
#define VOFF  ((size_t)2 * RTOT * DMODEL)
#define OOFF  ((size_t)3 * RTOT * DMODEL)
#define WOFF  ((size_t)4 * RTOT * DMODEL)   // W-fragment cache (128 KB)

#if __has_builtin(__builtin_amdgcn_exp2f)
#define EXP2F(x) __builtin_amdgcn_exp2f(x)
#else
#define EXP2F(x) exp2f(x)
#endif

typedef __attribute__((ext_vector_type(8)))  short short8;
typedef __attribute__((ext_vector_type(16))) float float16v;

static __device__ inline short8 as_s8(uint4 u) {
    union { uint4 u; short8 s; } x; x.u = u; return x.s;
}

static __device__ inline uint32_t bf162_bits(__hip_bfloat162 h) {
    union { __hip_bfloat162 h; uint32_t u; } x; x.h = h; return x.u;
}

// Split 8 fp32 into packed bf16 hi (RNE) + bf16 lo (exact residual, RNE).
static __device__ inline void split_pack8(const float* v, uint4* hi, uint4* lo) {
    uint32_t h[4], l[4];
    #pragma unroll
    for (int t = 0; t < 4; ++t) {
        float x0 = v[2 * t], x1 = v[2 * t + 1];
        uint32_t hw = bf162_bits(__float22bfloat162_rn(make_float2(x0, x1)));
        float h0 = __uint_as_float(hw << 16);
        float h1 = __uint_as_float(hw & 0xffff0000u);
        h[t] = hw;
        float l0 = x0 - h0;
        float l1 = x1 - h1;
        l[t] = bf162_bits(__float22bfloat162_rn(make_float2(l0, l1)));
    }
    *hi = make_uint4(h[0], h[1], h[2], h[3]);
    *lo = make_uint4(l[0], l[1], l[2], l[3]);
}

// ---------------------------------------------------------------------------
// Kernel 0: pre-split W7/8/9 (K=128) and W10/W11 (K=64) into bf16 hi/lo
// B-fragment layout. [0,3072) = W789; [3072,4096) = W10|W11.
// ---------------------------------------------------------------------------
__global__ __launch_bounds__(256) void wprep_kernel(
    const float* __restrict__ W7, const float* __restrict__ W8,
    const float* __restrict__ W9, const float* __restrict__ W10,
    const float* __restrict__ W11,
    uint4* __restrict__ WfH, uint4* __restrict__ WfL)
{
    const int e = blockIdx.x * 256 + threadIdx.x;   // 0..4095
    const float* W;
    int k0, col;
    if (e < 3072) {
        int n  = e & 31;
        int t  = (e >> 5) & 1;
        int hh = (e >> 6) & 1;
        int c  = (e >> 7) & 7;
        int w  = e >> 10;
        W = (w == 0) ? W7 : (w == 1) ? W8 : W9;
        k0 = c * 16 + hh * 8;
        col = t * 32 + n;
    } else {
        int pe = e - 3072;
        int n  = pe & 31;
        int t  = (pe >> 5) & 1;
        int hh = (pe >> 6) & 1;
        int c  = (pe >> 7) & 3;
        int m  = pe >> 9;
        W = (m == 0) ? W10 : W11;
        k0 = c * 16 + hh * 8;
        col = t * 32 + n;
    }
    float v[8];
    #pragma unroll
    for (int j = 0; j < 8; ++j) v[j] = W[(size_t)(k0 + j) * 64 + col];
    uint4 hi, lo;
    split_pack8(v, &hi, &lo);
    WfH[e] = hi;
    WfL[e] = lo;
}

// ---------------------------------------------------------------------------
// Kernel 1 (R7): MFMA QKV, w-split across blockIdx.y -> 3x wave count
// (4608 waves, ~18/CU). Per wave: 32 rows x 64 cols of ONE of Q/K/V.
// 4 accumulator chains (2 col-tiles x {main, corr}).
// ---------------------------------------------------------------------------
__global__ __launch_bounds__(64) void qkv_kernel(
    const float* __restrict__ X, const float* __restrict__ STE,
    const uint4* __restrict__ WfH, const uint4* __restrict__ WfL,
    const float* __restrict__ b7, const float* __restrict__ b8,
    const float* __restrict__ b9,
    float* __restrict__ qkv)
{
    const int lane = threadIdx.x;
    const int l31  = lane & 31;
    const int hh   = lane >> 5;
    const int w    = blockIdx.y;
    const size_t row = (size_t)blockIdx.x * 32 + l31;

    float16v accM[2], accC[2];
    #pragma unroll
    for (int t = 0; t < 2; ++t)
        #pragma unroll
        for (int i = 0; i < 16; ++i) { accM[t][i] = 0.f; accC[t][i] = 0.f; }

    #pragma unroll 4
    for (int c = 0; c < 8; ++c) {
        const float* src = (c < 4) ? X : STE;
        const int off = (c & 3) * 16 + hh * 8;
        const float* ap = src + row * 64 + off;
        float av[8];
        {
            float4 a0 = *(const float4*)(ap);
            float4 a1 = *(const float4*)(ap + 4);
            av[0] = a0.x; av[1] = a0.y; av[2] = a0.z; av[3] = a0.w;
            av[4] = a1.x; av[5] = a1.y; av[6] = a1.z; av[7] = a1.w;
        }
        uint4 ahi, alo;
        split_pack8(av, &ahi, &alo);

        #pragma unroll
        for (int t = 0; t < 2; ++t) {
            const int ei = w * 1024 + c * 128 + hh * 64 + t * 32 + l31;
            const uint4 bh = WfH[ei];
            const uint4 bl = WfL[ei];
            accM[t] = __builtin_amdgcn_mfma_f32_32x32x16_bf16(
                as_s8(ahi), as_s8(bh), accM[t], 0, 0, 0);
            accC[t] = __builtin_amdgcn_mfma_f32_32x32x16_bf16(
                as_s8(alo), as_s8(bh), accC[t], 0, 0, 0);
            accC[t] = __builtin_amdgcn_mfma_f32_32x32x16_bf16(
                as_s8(ahi), as_s8(bl), accC[t], 0, 0, 0);
        }
    }

    const float* bv = (w == 0) ? b7 : (w == 1) ? b8 : b9;
    float* obase = qkv + (size_t)w * ((size_t)RTOT * DMODEL);
    const size_t blockrow = (size_t)blockIdx.x * 32;
    #pragma unroll
    for (int t = 0; t < 2; ++t) {
        const int col = t * 32 + l31;
        const float bias = bv[col];
        #pragma unroll
        for (int r = 0; r < 16; ++r) {
            const int rowC = (r & 3) + 8 * (r >> 2) + 4 * hh;
            obase[(blockrow + rowC) * 64 + col] =
                fmaxf(accM[t][r] + accC[t][r] + bias, 0.f);
        }
    }
}

// ---------------------------------------------------------------------------
// Kernel 2 (R7): MFMA attention.
//  - 1536 blocks: each (bt,head) split into 2 q-halves -> 2x blocks/CU.
//  - 2 independent O accumulators (keys 0-15 / 16-31): chain depth 6 -> 3.
//  - S via 2 independent mfmas + fp32 add (no serial S chain).
//  - ak2p stride-33 with zero column: a2 index select hoisted out of loop.
// ---------------------------------------------------------------------------
__global__ __launch_bounds__(256) void attn_kernel(
    const float* __restrict__ qkv, float* __restrict__ obuf)
{
    __shared__ uint4 ak1[16 * 32];    //  8.0 KB  k_hi
    __shared__ uint4 ak2p[16 * 33];   //  8.3 KB  k_lo | zero column
    __shared__ uint4 vfh[640];        // 10.0 KB  V_hi frags (+zero pad)
    __shared__ uint4 vfl[640];        // 10.0 KB  V_lo frags (+zero pad)

    const int tid  = threadIdx.x;
    const int lane = tid & 63;
    const int l31  = lane & 31;
    const int hh   = lane >> 5;
    const int wv   = tid >> 6;
    const int qh   = blockIdx.x & 1;
    const int head = (blockIdx.x >> 1) & 7;
    const int bt   = blockIdx.x >> 4;

    const size_t rowbase = (size_t)bt * NSEQ * 64 + (size_t)head * 8;
    const float* Qp = qkv + QOFF + rowbase;
    const float* Kp = qkv + KOFF + rowbase;
    const float* Vp = qkv + VOFF + rowbase;

    const uint4 z4 = make_uint4(0, 0, 0, 0);

    for (int k = tid; k < NSEQ; k += 256) {
        const float* kr = Kp + (size_t)k * 64;
        float kv[8];
        float4 a = *(const float4*)(kr);
        float4 b = *(const float4*)(kr + 4);
        kv[0] = a.x; kv[1] = a.y; kv[2] = a.z; kv[3] = a.w;
        kv[4] = b.x; kv[5] = b.y; kv[6] = b.z; kv[7] = b.w;
        uint4 hi, lo;
        split_pack8(kv, &hi, &lo);
        ak1[k] = hi;
        ak2p[(k >> 5) * 33 + (k & 31)] = lo;
    }
    if (tid < 16) ak2p[tid * 33 + 32] = z4;

    for (int e = tid; e < 640; e += 256) {
        if (e < 576) {
            int s  = e / 18;
            int r  = e % 18;
            int hv = r / 9;
            int n  = r % 9;
            float vv[8];
            #pragma unroll
            for (int j = 0; j < 8; ++j) {
                int key = 16 * s + ((j < 4) ? (4 * hv + j) : (8 + 4 * hv + (j - 4)));
                vv[j] = (n < 8) ? Vp[(size_t)key * 64 + n] : 1.0f;
            }
            uint4 hi, lo;
            split_pack8(vv, &hi, &lo);
            vfh[e] = hi;
            vfl[e] = lo;
        } else {
            vfh[e] = z4;
            vfl[e] = z4;
        }
    }

    __syncthreads();

    const float C = 0.51012091684045906f;  // log2(e)/sqrt(8)
    const int idx2 = hh ? 32 : l31;        // zero column for hh=1 lanes

    float16v Z16;
    #pragma unroll
    for (int i = 0; i < 16; ++i) Z16[i] = 0.f;

    #pragma unroll
    for (int qq = 0; qq < 2; ++qq) {
        const int qt = qh * 8 + wv + qq * 4;
        const float* qp = Qp + (size_t)(qt * 32 + l31) * 64;
        float qv[8];
        {
            float4 a = *(const float4*)(qp);
            float4 b = *(const float4*)(qp + 4);
            qv[0] = a.x * C; qv[1] = a.y * C; qv[2] = a.z * C; qv[3] = a.w * C;
            qv[4] = b.x * C; qv[5] = b.y * C; qv[6] = b.z * C; qv[7] = b.w * C;
        }
        uint4 qhi, qlo;
        split_pack8(qv, &qhi, &qlo);
        const uint4 bq1 = hh ? qlo : qhi;
        const uint4 bq2 = qhi;

        float16v Oa = Z16, Ob = Z16;

        for (int c = 0; c < 16; ++c) {
            const uint4 a1 = ak1[c * 32 + l31];
            const uint4 a2 = ak2p[c * 33 + idx2];
            const int vi0 = (4 * c + hh) * 9;
            const int vi1 = (4 * c + 2 + hh) * 9;
            const uint4 bh0 = vfh[vi0 + l31];
            const uint4 bl0 = vfl[vi0 + l31];
            const uint4 bh1 = vfh[vi1 + l31];
            const uint4 bl1 = vfl[vi1 + l31];

            float16v S1, S2;
            S1 = __builtin_amdgcn_mfma_f32_32x32x16_bf16(as_s8(a1), as_s8(bq1), Z16, 0, 0, 0);
            S2 = __builtin_amdgcn_mfma_f32_32x32x16_bf16(as_s8(a2), as_s8(bq2), Z16, 0, 0, 0);

            float pv[16];
            #pragma unroll
            for (int i = 0; i < 16; ++i) pv[i] = EXP2F(S1[i] + S2[i]);

            uint4 ph0, pl0, ph1, pl1;
            split_pack8(&pv[0], &ph0, &pl0);
            split_pack8(&pv[8], &ph1, &pl1);

            // keys 0-15 -> Oa, keys 16-31 -> Ob (independent chains)
            Oa = __builtin_amdgcn_mfma_f32_32x32x16_bf16(as_s8(ph0), as_s8(bh0), Oa, 0, 0, 0);
            Ob = __builtin_amdgcn_mfma_f32_32x32x16_bf16(as_s8(ph1), as_s8(bh1), Ob, 0, 0, 0);
            Oa = __builtin_amdgcn_mfma_f32_32x32x16_bf16(as_s8(pl0), as_s8(bh0), Oa, 0, 0, 0);
            Ob = __builtin_amdgcn_mfma_f32_32x32x16_bf16(as_s8(pl1), as_s8(bh1), Ob, 0, 0, 0);
            Oa = __builtin_amdgcn_mfma_f32_32x32x16_bf16(as_s8(ph0), as_s8(bl0), Oa, 0, 0, 0);
            Ob = __builtin_amdgcn_mfma_f32_32x32x16_bf16(as_s8(ph1), as_s8(bl1), Ob, 0, 0, 0);
        }

        #pragma unroll
        for (int r = 0; r < 16; ++r) {
            float ov = Oa[r] + Ob[r];
            float den = __uint_as_float(
                __builtin_amdgcn_ds_swizzle(__float_as_uint(ov), 0x100));
            float o = ov / den;
            if (l31 < 8) {
                int row = (r & 3) + 8 * (r >> 2) + 4 * hh;
                obuf[rowbase + (size_t)(qt * 32 + row) * 64 + l31] = o;
            }
        }
    }
}

// ---------------------------------------------------------------------------
// Kernel 3 (R7): 64x64 linear, t-split across blockIdx.y -> 2x wave count
// (3072 waves, ~12/CU). Per wave: 32 rows x 32 cols. main/corr acc chains.
// ---------------------------------------------------------------------------
__global__ __launch_bounds__(64) void lin64_kernel(
    const float* __restrict__ inp,
    const uint4* __restrict__ WfH, const uint4* __restrict__ WfL,
    const float* __restrict__ bias,
    float* __restrict__ outp, int do_relu)
{
    const int lane = threadIdx.x;
    const int l31  = lane & 31;
    const int hh   = lane >> 5;
    const int t    = blockIdx.y;
    const size_t row = (size_t)blockIdx.x * 32 + l31;

    float16v accM, accC;
    #pragma unroll
    for (int i = 0; i < 16; ++i) { accM[i] = 0.f; accC[i] = 0.f; }

    #pragma unroll
    for (int c = 0; c < 4; ++c) {
        const float* ap = inp + row * 64 + c * 16 + hh * 8;
        float av[8];
        {
            float4 a0 = *(const float4*)(ap);
            float4 a1 = *(const float4*)(ap + 4);
            av[0] = a0.x; av[1] = a0.y; av[2] = a0.z; av[3] = a0.w;
            av[4] = a1.x; av[5] = a1.y; av[6] = a1.z; av[7] = a1.w;
        }
        uint4 ahi, alo;
        split_pack8(av, &ahi, &alo);

        const int ei = c * 128 + hh * 64 + t * 32 + l31;
        const uint4 bh = WfH[ei];
        const uint4 bl = WfL[ei];
        accM = __builtin_amdgcn_mfma_f32_32x32x16_bf16(as_s8(ahi), as_s8(bh), accM, 0, 0, 0);
        accC = __builtin_amdgcn_mfma_f32_32x32x16_bf16(as_s8(alo), as_s8(bh), accC, 0, 0, 0);
        accC = __builtin_amdgcn_mfma_f32_32x32x16_bf16(as_s8(ahi), as_s8(bl), accC, 0, 0, 0);
    }

    const size_t blockrow = (size_t)blockIdx.x * 32;
    const int col = t * 32 + l31;
    const float b = bias[col];
    #pragma unroll
    for (int r = 0; r < 16; ++r) {
        const int rowC = (r & 3) + 8 * (r >> 2) + 4 * hh;
        float v = accM[r] + accC[r] + b;
        if (do_relu) v = fmaxf(v, 0.f);
        outp[(blockrow + rowC) * 64 + col] = v;
    }
}

// ---------------------------------------------------------------------------
extern "C" void kernel_launch(void* const* d_in, const int* in_sizes, int n_in,
                              void* d_out, int out_size, void* d_ws, size_t ws_size,
                              hipStream_t stream)
{
    const float* X   = (const float*)d_in[0];
    const float* STE = (const float*)d_in[1];
    const float* W7  = (const float*)d_in[2];
    const float* b7  = (const float*)d_in[3];
    const float* W8  = (const float*)d_in[4];
    const float* b8  = (const float*)d_in[5];
    const float* W9  = (const float*)d_in[6];
    const float* b9  = (const float*)d_in[7];
    const float* W10 = (const float*)d_in[8];
    const float* b10 = (const float*)d_in[9];
    const float* W11 = (const float*)d_in[10];
    const float* b11 = (const float*)d_in[11];

    float* ws  = (float*)d_ws;   // Q | K | V | O | Wf
    float* out = (float*)d_out;

    uint4* WfH = (uint4*)(ws + WOFF);
    uint4* WfL = WfH + 4096;

    wprep_kernel<<<dim3(16), 256, 0, stream>>>(W7, W8, W9, W10, W11, WfH, WfL);
    qkv_kernel<<<dim3(RTOT / 32, 3), 64, 0, stream>>>(X, STE, WfH, WfL, b7, b8, b9, ws);
    attn_kernel<<<dim3(BT * 8 * 2), 256, 0, stream>>>(ws, ws + OOFF);
    // T = relu(O @ W10 + b10) -> reuse Q region
    lin64_kernel<<<dim3(RTOT / 32, 2), 64, 0, stream>>>(
        ws + OOFF, WfH + 3072, WfL + 3072, b10, ws + QOFF, 1);
    // out = T @ W11 + b11
    lin64_kernel<<<dim3(RTOT / 32, 2), 64, 0, stream>>>(
        ws + QOFF, WfH + 3584, WfL + 3584, b11, out, 0);
}

// Round 8
// 213.080 us; speedup vs baseline: 1.0737x; 1.0737x over previous
//
#include <hip/hip_runtime.h>
#include <hip/hip_bf16.h>
#include <math.h>

// Problem constants
#define BT    96          // B*T = 8*12
#define NSEQ  512         // N
#define DMODEL 64         // D = K*d
#define RTOT  (BT * NSEQ) // 49152 rows

// Workspace layout (floats)
#define QOFF  0
#define KOFF  ((size_t)RTOT * DMODEL)
#define VOFF  ((size_t)2 * RTOT * DMODEL)
#define OOFF  ((size_t)3 * RTOT * DMODEL)
#define WOFF  ((size_t)4 * RTOT * DMODEL)   // W-fragment cache (128 KB)

// Guaranteed single-instruction 2^x.
static __device__ inline float fast_exp2(float x) {
#if __has_builtin(__builtin_amdgcn_exp2f)
    return __builtin_amdgcn_exp2f(x);
#else
    float r; asm("v_exp_f32 %0, %1" : "=v"(r) : "v"(x)); return r;
#endif
}

typedef __attribute__((ext_vector_type(8)))  short short8;
typedef __attribute__((ext_vector_type(16))) float float16v;

static __device__ inline short8 as_s8(uint4 u) {
    union { uint4 u; short8 s; } x; x.u = u; return x.s;
}

static __device__ inline uint32_t bf162_bits(__hip_bfloat162 h) {
    union { __hip_bfloat162 h; uint32_t u; } x; x.h = h; return x.u;
}

// Split 8 fp32 into packed bf16 hi (RNE) + bf16 lo (exact residual, RNE).
static __device__ inline void split_pack8(const float* v, uint4* hi, uint4* lo) {
    uint32_t h[4], l[4];
    #pragma unroll
    for (int t = 0; t < 4; ++t) {
        float x0 = v[2 * t], x1 = v[2 * t + 1];
        uint32_t hw = bf162_bits(__float22bfloat162_rn(make_float2(x0, x1)));
        float h0 = __uint_as_float(hw << 16);
        float h1 = __uint_as_float(hw & 0xffff0000u);
        h[t] = hw;
        float l0 = x0 - h0;
        float l1 = x1 - h1;
        l[t] = bf162_bits(__float22bfloat162_rn(make_float2(l0, l1)));
    }
    *hi = make_uint4(h[0], h[1], h[2], h[3]);
    *lo = make_uint4(l[0], l[1], l[2], l[3]);
}

// ---------------------------------------------------------------------------
// Kernel 0: pre-split W7/8/9 (K=128) and W10/W11 (K=64) into bf16 hi/lo
// B-fragment layout. [0,3072) = W789; [3072,3584) = W10; [3584,4096) = W11.
// ---------------------------------------------------------------------------
__global__ __launch_bounds__(256) void wprep_kernel(
    const float* __restrict__ W7, const float* __restrict__ W8,
    const float* __restrict__ W9, const float* __restrict__ W10,
    const float* __restrict__ W11,
    uint4* __restrict__ WfH, uint4* __restrict__ WfL)
{
    const int e = blockIdx.x * 256 + threadIdx.x;   // 0..4095
    const float* W;
    int k0, col;
    if (e < 3072) {
        int n  = e & 31;
        int t  = (e >> 5) & 1;
        int hh = (e >> 6) & 1;
        int c  = (e >> 7) & 7;
        int w  = e >> 10;
        W = (w == 0) ? W7 : (w == 1) ? W8 : W9;
        k0 = c * 16 + hh * 8;
        col = t * 32 + n;
    } else {
        int pe = e - 3072;
        int n  = pe & 31;
        int t  = (pe >> 5) & 1;
        int hh = (pe >> 6) & 1;
        int c  = (pe >> 7) & 3;
        int m  = pe >> 9;
        W = (m == 0) ? W10 : W11;
        k0 = c * 16 + hh * 8;
        col = t * 32 + n;
    }
    float v[8];
    #pragma unroll
    for (int j = 0; j < 8; ++j) v[j] = W[(size_t)(k0 + j) * 64 + col];
    uint4 hi, lo;
    split_pack8(v, &hi, &lo);
    WfH[e] = hi;
    WfL[e] = lo;
}

// ---------------------------------------------------------------------------
// Kernel 1 (R7, kept): MFMA QKV, w-split across blockIdx.y (4608 waves).
// ---------------------------------------------------------------------------
__global__ __launch_bounds__(64) void qkv_kernel(
    const float* __restrict__ X, const float* __restrict__ STE,
    const uint4* __restrict__ WfH, const uint4* __restrict__ WfL,
    const float* __restrict__ b7, const float* __restrict__ b8,
    const float* __restrict__ b9,
    float* __restrict__ qkv)
{
    const int lane = threadIdx.x;
    const int l31  = lane & 31;
    const int hh   = lane >> 5;
    const int w    = blockIdx.y;
    const size_t row = (size_t)blockIdx.x * 32 + l31;

    float16v accM[2], accC[2];
    #pragma unroll
    for (int t = 0; t < 2; ++t)
        #pragma unroll
        for (int i = 0; i < 16; ++i) { accM[t][i] = 0.f; accC[t][i] = 0.f; }

    #pragma unroll
    for (int c = 0; c < 8; ++c) {
        const float* src = (c < 4) ? X : STE;
        const int off = (c & 3) * 16 + hh * 8;
        const float* ap = src + row * 64 + off;
        float av[8];
        {
            float4 a0 = *(const float4*)(ap);
            float4 a1 = *(const float4*)(ap + 4);
            av[0] = a0.x; av[1] = a0.y; av[2] = a0.z; av[3] = a0.w;
            av[4] = a1.x; av[5] = a1.y; av[6] = a1.z; av[7] = a1.w;
        }
        uint4 ahi, alo;
        split_pack8(av, &ahi, &alo);

        #pragma unroll
        for (int t = 0; t < 2; ++t) {
            const int ei = w * 1024 + c * 128 + hh * 64 + t * 32 + l31;
            const uint4 bh = WfH[ei];
            const uint4 bl = WfL[ei];
            accM[t] = __builtin_amdgcn_mfma_f32_32x32x16_bf16(
                as_s8(ahi), as_s8(bh), accM[t], 0, 0, 0);
            accC[t] = __builtin_amdgcn_mfma_f32_32x32x16_bf16(
                as_s8(alo), as_s8(bh), accC[t], 0, 0, 0);
            accC[t] = __builtin_amdgcn_mfma_f32_32x32x16_bf16(
                as_s8(ahi), as_s8(bl), accC[t], 0, 0, 0);
        }
    }

    const float* bv = (w == 0) ? b7 : (w == 1) ? b8 : b9;
    float* obase = qkv + (size_t)w * ((size_t)RTOT * DMODEL);
    const size_t blockrow = (size_t)blockIdx.x * 32;
    #pragma unroll
    for (int t = 0; t < 2; ++t) {
        const int col = t * 32 + l31;
        const float bias = bv[col];
        #pragma unroll
        for (int r = 0; r < 16; ++r) {
            const int rowC = (r & 3) + 8 * (r >> 2) + 4 * hh;
            obase[(blockrow + rowC) * 64 + col] =
                fmaxf(accM[t][r] + accC[t][r] + bias, 0.f);
        }
    }
}

// ---------------------------------------------------------------------------
// Kernel 2 (R8): attention = R5 structure (768 blocks, 4 qt/wave, single
// K/V staging) + deltas: fully unrolled chunk loop (immediate LDS offsets),
// chained S (add via MFMA C-input), 2 independent O chains, raw v_exp_f32.
// ---------------------------------------------------------------------------
__global__ __launch_bounds__(256) void attn_kernel(
    const float* __restrict__ qkv, float* __restrict__ obuf)
{
    __shared__ uint4 ak1[16 * 32];    // 8 KB k_hi
    __shared__ uint4 ak2[16 * 32];    // 8 KB k_lo
    __shared__ uint4 vfh[576];        // 9 KB V_hi frags
    __shared__ uint4 vfl[576];        // 9 KB V_lo frags
    __shared__ uint4 zslab;

    const int tid  = threadIdx.x;
    const int lane = tid & 63;
    const int l31  = lane & 31;
    const int hh   = lane >> 5;
    const int wv   = tid >> 6;
    const int head = blockIdx.x & 7;
    const int bt   = blockIdx.x >> 3;

    const size_t rowbase = (size_t)bt * NSEQ * 64 + (size_t)head * 8;
    const float* Qp = qkv + QOFF + rowbase;
    const float* Kp = qkv + KOFF + rowbase;
    const float* Vp = qkv + VOFF + rowbase;

    if (tid == 0) zslab = make_uint4(0, 0, 0, 0);

    #pragma unroll
    for (int kk = 0; kk < 2; ++kk) {
        const int k = tid + kk * 256;
        const float* kr = Kp + (size_t)k * 64;
        float kv[8];
        float4 a = *(const float4*)(kr);
        float4 b = *(const float4*)(kr + 4);
        kv[0] = a.x; kv[1] = a.y; kv[2] = a.z; kv[3] = a.w;
        kv[4] = b.x; kv[5] = b.y; kv[6] = b.z; kv[7] = b.w;
        uint4 hi, lo;
        split_pack8(kv, &hi, &lo);
        ak1[k] = hi;
        ak2[k] = lo;
    }

    for (int e = tid; e < 576; e += 256) {
        int s  = e / 18;
        int r  = e % 18;
        int hv = r / 9;
        int n  = r % 9;
        float vv[8];
        #pragma unroll
        for (int j = 0; j < 8; ++j) {
            int key = 16 * s + ((j < 4) ? (4 * hv + j) : (8 + 4 * hv + (j - 4)));
            vv[j] = (n < 8) ? Vp[(size_t)key * 64 + n] : 1.0f;
        }
        uint4 hi, lo;
        split_pack8(vv, &hi, &lo);
        vfh[e] = hi;
        vfl[e] = lo;
    }

    __syncthreads();

    const float C = 0.51012091684045906f;  // log2(e)/sqrt(8)

    float16v Z16;
    #pragma unroll
    for (int i = 0; i < 16; ++i) Z16[i] = 0.f;

    for (int qt = wv; qt < 16; qt += 4) {
        const float* qp = Qp + (size_t)(qt * 32 + l31) * 64;
        float qv[8];
        {
            float4 a = *(const float4*)(qp);
            float4 b = *(const float4*)(qp + 4);
            qv[0] = a.x * C; qv[1] = a.y * C; qv[2] = a.z * C; qv[3] = a.w * C;
            qv[4] = b.x * C; qv[5] = b.y * C; qv[6] = b.z * C; qv[7] = b.w * C;
        }
        uint4 qhi, qlo;
        split_pack8(qv, &qhi, &qlo);
        const uint4 bq1 = hh ? qlo : qhi;
        const uint4 bq2 = qhi;

        float16v Oa = Z16, Ob = Z16;

        #pragma unroll
        for (int c = 0; c < 16; ++c) {
            const uint4 a1 = ak1[c * 32 + l31];
            const uint4 a2 = hh ? zslab : ak2[c * 32 + l31];
            const int vi0 = (4 * c + hh) * 9;
            const int vi1 = (4 * c + 2 + hh) * 9;
            const bool act = (l31 < 9);
            const uint4 bh0 = act ? vfh[vi0 + l31] : zslab;
            const uint4 bl0 = act ? vfl[vi0 + l31] : zslab;
            const uint4 bh1 = act ? vfh[vi1 + l31] : zslab;
            const uint4 bl1 = act ? vfl[vi1 + l31] : zslab;

            float16v S;
            S = __builtin_amdgcn_mfma_f32_32x32x16_bf16(as_s8(a1), as_s8(bq1), Z16, 0, 0, 0);
            S = __builtin_amdgcn_mfma_f32_32x32x16_bf16(as_s8(a2), as_s8(bq2), S, 0, 0, 0);

            float pv[16];
            #pragma unroll
            for (int i = 0; i < 16; ++i) pv[i] = fast_exp2(S[i]);

            uint4 ph0, pl0, ph1, pl1;
            split_pack8(&pv[0], &ph0, &pl0);
            split_pack8(&pv[8], &ph1, &pl1);

            Oa = __builtin_amdgcn_mfma_f32_32x32x16_bf16(as_s8(ph0), as_s8(bh0), Oa, 0, 0, 0);
            Ob = __builtin_amdgcn_mfma_f32_32x32x16_bf16(as_s8(ph1), as_s8(bh1), Ob, 0, 0, 0);
            Oa = __builtin_amdgcn_mfma_f32_32x32x16_bf16(as_s8(pl0), as_s8(bh0), Oa, 0, 0, 0);
            Ob = __builtin_amdgcn_mfma_f32_32x32x16_bf16(as_s8(pl1), as_s8(bh1), Ob, 0, 0, 0);
            Oa = __builtin_amdgcn_mfma_f32_32x32x16_bf16(as_s8(ph0), as_s8(bl0), Oa, 0, 0, 0);
            Ob = __builtin_amdgcn_mfma_f32_32x32x16_bf16(as_s8(ph1), as_s8(bl1), Ob, 0, 0, 0);
        }

        #pragma unroll
        for (int r = 0; r < 16; ++r) {
            float ov = Oa[r] + Ob[r];
            float den = __uint_as_float(
                __builtin_amdgcn_ds_swizzle(__float_as_uint(ov), 0x100));
            float o = ov / den;
            if (l31 < 8) {
                int row = (r & 3) + 8 * (r >> 2) + 4 * hh;
                obuf[rowbase + (size_t)(qt * 32 + row) * 64 + l31] = o;
            }
        }
    }
}

// ---------------------------------------------------------------------------
// Kernel 3 (R8): fused projection. One wave / 32 rows:
//   T = relu(O @ W10 + b10)  -> LDS (32x68 fp32)  ->  out = T @ W11 + b11.
// Saves the T HBM round-trip (25 MB) and one launch.
// ---------------------------------------------------------------------------
__global__ __launch_bounds__(64) void proj_kernel(
    const float* __restrict__ obuf,
    const uint4* __restrict__ WfH, const uint4* __restrict__ WfL,
    const float* __restrict__ b10, const float* __restrict__ b11,
    float* __restrict__ out)
{
    __shared__ float Ts[32][68];   // 8.7 KB, rows 272B (16B-aligned)

    const int lane = threadIdx.x;
    const int l31  = lane & 31;
    const int hh   = lane >> 5;
    const size_t row = (size_t)blockIdx.x * 32 + l31;
    const size_t blockrow = (size_t)blockIdx.x * 32;

    // ---- GEMM1: T = relu(O @ W10 + b10) ----
    float16v accM[2], accC[2];
    #pragma unroll
    for (int t = 0; t < 2; ++t)
        #pragma unroll
        for (int i = 0; i < 16; ++i) { accM[t][i] = 0.f; accC[t][i] = 0.f; }

    #pragma unroll
    for (int c = 0; c < 4; ++c) {
        const float* ap = obuf + row * 64 + c * 16 + hh * 8;
        float av[8];
        {
            float4 a0 = *(const float4*)(ap);
            float4 a1 = *(const float4*)(ap + 4);
            av[0] = a0.x; av[1] = a0.y; av[2] = a0.z; av[3] = a0.w;
            av[4] = a1.x; av[5] = a1.y; av[6] = a1.z; av[7] = a1.w;
        }
        uint4 ahi, alo;
        split_pack8(av, &ahi, &alo);

        #pragma unroll
        for (int t = 0; t < 2; ++t) {
            const int ei = 3072 + c * 128 + hh * 64 + t * 32 + l31;   // W10
            const uint4 bh = WfH[ei];
            const uint4 bl = WfL[ei];
            accM[t] = __builtin_amdgcn_mfma_f32_32x32x16_bf16(
                as_s8(ahi), as_s8(bh), accM[t], 0, 0, 0);
            accC[t] = __builtin_amdgcn_mfma_f32_32x32x16_bf16(
                as_s8(alo), as_s8(bh), accC[t], 0, 0, 0);
            accC[t] = __builtin_amdgcn_mfma_f32_32x32x16_bf16(
                as_s8(ahi), as_s8(bl), accC[t], 0, 0, 0);
        }
    }

    #pragma unroll
    for (int t = 0; t < 2; ++t) {
        const int col = t * 32 + l31;
        const float bias = b10[col];
        #pragma unroll
        for (int r = 0; r < 16; ++r) {
            const int rowC = (r & 3) + 8 * (r >> 2) + 4 * hh;
            Ts[rowC][col] = fmaxf(accM[t][r] + accC[t][r] + bias, 0.f);
        }
    }
    __syncthreads();   // single wave: compiles to lgkmcnt drain

    // ---- GEMM2: out = T @ W11 + b11 ----
    #pragma unroll
    for (int t = 0; t < 2; ++t)
        #pragma unroll
        for (int i = 0; i < 16; ++i) { accM[t][i] = 0.f; accC[t][i] = 0.f; }

    #pragma unroll
    for (int c = 0; c < 4; ++c) {
        const float* ap = &Ts[l31][c * 16 + hh * 8];
        float av[8];
        {
            float4 a0 = *(const float4*)(ap);
            float4 a1 = *(const float4*)(ap + 4);
            av[0] = a0.x; av[1] = a0.y; av[2] = a0.z; av[3] = a0.w;
            av[4] = a1.x; av[5] = a1.y; av[6] = a1.z; av[7] = a1.w;
        }
        uint4 ahi, alo;
        split_pack8(av, &ahi, &alo);

        #pragma unroll
        for (int t = 0; t < 2; ++t) {
            const int ei = 3584 + c * 128 + hh * 64 + t * 32 + l31;   // W11
            const uint4 bh = WfH[ei];
            const uint4 bl = WfL[ei];
            accM[t] = __builtin_amdgcn_mfma_f32_32x32x16_bf16(
                as_s8(ahi), as_s8(bh), accM[t], 0, 0, 0);
            accC[t] = __builtin_amdgcn_mfma_f32_32x32x16_bf16(
                as_s8(alo), as_s8(bh), accC[t], 0, 0, 0);
            accC[t] = __builtin_amdgcn_mfma_f32_32x32x16_bf16(
                as_s8(ahi), as_s8(bl), accC[t], 0, 0, 0);
        }
    }

    #pragma unroll
    for (int t = 0; t < 2; ++t) {
        const int col = t * 32 + l31;
        const float bias = b11[col];
        #pragma unroll
        for (int r = 0; r < 16; ++r) {
            const int rowC = (r & 3) + 8 * (r >> 2) + 4 * hh;
            out[(blockrow + rowC) * 64 + col] = accM[t][r] + accC[t][r] + bias;
        }
    }
}

// ---------------------------------------------------------------------------
extern "C" void kernel_launch(void* const* d_in, const int* in_sizes, int n_in,
                              void* d_out, int out_size, void* d_ws, size_t ws_size,
                              hipStream_t stream)
{
    const float* X   = (const float*)d_in[0];
    const float* STE = (const float*)d_in[1];
    const float* W7  = (const float*)d_in[2];
    const float* b7  = (const float*)d_in[3];
    const float* W8  = (const float*)d_in[4];
    const float* b8  = (const float*)d_in[5];
    const float* W9  = (const float*)d_in[6];
    const float* b9  = (const float*)d_in[7];
    const float* W10 = (const float*)d_in[8];
    const float* b10 = (const float*)d_in[9];
    const float* W11 = (const float*)d_in[10];
    const float* b11 = (const float*)d_in[11];

    float* ws  = (float*)d_ws;   // Q | K | V | O | Wf
    float* out = (float*)d_out;

    uint4* WfH = (uint4*)(ws + WOFF);
    uint4* WfL = WfH + 4096;

    wprep_kernel<<<dim3(16), 256, 0, stream>>>(W7, W8, W9, W10, W11, WfH, WfL);
    qkv_kernel<<<dim3(RTOT / 32, 3), 64, 0, stream>>>(X, STE, WfH, WfL, b7, b8, b9, ws);
    attn_kernel<<<dim3(BT * 8), 256, 0, stream>>>(ws, ws + OOFF);
    proj_kernel<<<dim3(RTOT / 32), 64, 0, stream>>>(ws + OOFF, WfH, WfL, b10, b11, out);
}

// Round 10
// 192.742 us; speedup vs baseline: 1.1870x; 1.1055x over previous
//
#include <hip/hip_runtime.h>
#include <hip/hip_bf16.h>
#include <math.h>

// Problem constants
#define BT    96          // B*T = 8*12
#define NSEQ  512         // N
#define DMODEL 64         // D = K*d
#define RTOT  (BT * NSEQ) // 49152 rows

// Workspace layout (floats)
#define QOFF  0
#define KOFF  ((size_t)RTOT * DMODEL)
#define VOFF  ((size_t)2 * RTOT * DMODEL)
#define OOFF  ((size_t)3 * RTOT * DMODEL)
#define WOFF  ((size_t)4 * RTOT * DMODEL)   // W-fragment cache (128 KB)

// Guaranteed single-instruction 2^x / 1/x.
static __device__ inline float fast_exp2(float x) {
#if __has_builtin(__builtin_amdgcn_exp2f)
    return __builtin_amdgcn_exp2f(x);
#else
    float r; asm("v_exp_f32 %0, %1" : "=v"(r) : "v"(x)); return r;
#endif
}
static __device__ inline float fast_rcp(float x) {
#if __has_builtin(__builtin_amdgcn_rcpf)
    return __builtin_amdgcn_rcpf(x);
#else
    return 1.f / x;
#endif
}

typedef __attribute__((ext_vector_type(8)))  short short8;
typedef __attribute__((ext_vector_type(16))) float float16v;

static __device__ inline short8 as_s8(uint4 u) {
    union { uint4 u; short8 s; } x; x.u = u; return x.s;
}

static __device__ inline uint32_t bf162_bits(__hip_bfloat162 h) {
    union { __hip_bfloat162 h; uint32_t u; } x; x.h = h; return x.u;
}

// Split 8 fp32 into packed bf16 hi (RNE) + bf16 lo (exact residual, RNE).
static __device__ inline void split_pack8(const float* v, uint4* hi, uint4* lo) {
    uint32_t h[4], l[4];
    #pragma unroll
    for (int t = 0; t < 4; ++t) {
        float x0 = v[2 * t], x1 = v[2 * t + 1];
        uint32_t hw = bf162_bits(__float22bfloat162_rn(make_float2(x0, x1)));
        float h0 = __uint_as_float(hw << 16);
        float h1 = __uint_as_float(hw & 0xffff0000u);
        h[t] = hw;
        float l0 = x0 - h0;
        float l1 = x1 - h1;
        l[t] = bf162_bits(__float22bfloat162_rn(make_float2(l0, l1)));
    }
    *hi = make_uint4(h[0], h[1], h[2], h[3]);
    *lo = make_uint4(l[0], l[1], l[2], l[3]);
}

// ---------------------------------------------------------------------------
// Kernel 0: pre-split W7/8/9 (K=128) and W10/W11 (K=64) into bf16 hi/lo
// B-fragment layout. [0,3072) = W789; [3072,3584) = W10; [3584,4096) = W11.
// ---------------------------------------------------------------------------
__global__ __launch_bounds__(256) void wprep_kernel(
    const float* __restrict__ W7, const float* __restrict__ W8,
    const float* __restrict__ W9, const float* __restrict__ W10,
    const float* __restrict__ W11,
    uint4* __restrict__ WfH, uint4* __restrict__ WfL)
{
    const int e = blockIdx.x * 256 + threadIdx.x;   // 0..4095
    const float* W;
    int k0, col;
    if (e < 3072) {
        int n  = e & 31;
        int t  = (e >> 5) & 1;
        int hh = (e >> 6) & 1;
        int c  = (e >> 7) & 7;
        int w  = e >> 10;
        W = (w == 0) ? W7 : (w == 1) ? W8 : W9;
        k0 = c * 16 + hh * 8;
        col = t * 32 + n;
    } else {
        int pe = e - 3072;
        int n  = pe & 31;
        int t  = (pe >> 5) & 1;
        int hh = (pe >> 6) & 1;
        int c  = (pe >> 7) & 3;
        int m  = pe >> 9;
        W = (m == 0) ? W10 : W11;
        k0 = c * 16 + hh * 8;
        col = t * 32 + n;
    }
    float v[8];
    #pragma unroll
    for (int j = 0; j < 8; ++j) v[j] = W[(size_t)(k0 + j) * 64 + col];
    uint4 hi, lo;
    split_pack8(v, &hi, &lo);
    WfH[e] = hi;
    WfL[e] = lo;
}

// ---------------------------------------------------------------------------
// Kernel 1 (R7, kept): MFMA QKV, w-split across blockIdx.y (4608 waves).
// ---------------------------------------------------------------------------
__global__ __launch_bounds__(64) void qkv_kernel(
    const float* __restrict__ X, const float* __restrict__ STE,
    const uint4* __restrict__ WfH, const uint4* __restrict__ WfL,
    const float* __restrict__ b7, const float* __restrict__ b8,
    const float* __restrict__ b9,
    float* __restrict__ qkv)
{
    const int lane = threadIdx.x;
    const int l31  = lane & 31;
    const int hh   = lane >> 5;
    const int w    = blockIdx.y;
    const size_t row = (size_t)blockIdx.x * 32 + l31;

    float16v accM[2], accC[2];
    #pragma unroll
    for (int t = 0; t < 2; ++t)
        #pragma unroll
        for (int i = 0; i < 16; ++i) { accM[t][i] = 0.f; accC[t][i] = 0.f; }

    #pragma unroll
    for (int c = 0; c < 8; ++c) {
        const float* src = (c < 4) ? X : STE;
        const int off = (c & 3) * 16 + hh * 8;
        const float* ap = src + row * 64 + off;
        float av[8];
        {
            float4 a0 = *(const float4*)(ap);
            float4 a1 = *(const float4*)(ap + 4);
            av[0] = a0.x; av[1] = a0.y; av[2] = a0.z; av[3] = a0.w;
            av[4] = a1.x; av[5] = a1.y; av[6] = a1.z; av[7] = a1.w;
        }
        uint4 ahi, alo;
        split_pack8(av, &ahi, &alo);

        #pragma unroll
        for (int t = 0; t < 2; ++t) {
            const int ei = w * 1024 + c * 128 + hh * 64 + t * 32 + l31;
            const uint4 bh = WfH[ei];
            const uint4 bl = WfL[ei];
            accM[t] = __builtin_amdgcn_mfma_f32_32x32x16_bf16(
                as_s8(ahi), as_s8(bh), accM[t], 0, 0, 0);
            accC[t] = __builtin_amdgcn_mfma_f32_32x32x16_bf16(
                as_s8(alo), as_s8(bh), accC[t], 0, 0, 0);
            accC[t] = __builtin_amdgcn_mfma_f32_32x32x16_bf16(
                as_s8(ahi), as_s8(bl), accC[t], 0, 0, 0);
        }
    }

    const float* bv = (w == 0) ? b7 : (w == 1) ? b8 : b9;
    float* obase = qkv + (size_t)w * ((size_t)RTOT * DMODEL);
    const size_t blockrow = (size_t)blockIdx.x * 32;
    #pragma unroll
    for (int t = 0; t < 2; ++t) {
        const int col = t * 32 + l31;
        const float bias = bv[col];
        #pragma unroll
        for (int r = 0; r < 16; ++r) {
            const int rowC = (r & 3) + 8 * (r >> 2) + 4 * hh;
            obase[(blockrow + rowC) * 64 + col] =
                fmaxf(accM[t][r] + accC[t][r] + bias, 0.f);
        }
    }
}

// ---------------------------------------------------------------------------
// Kernel 2 (R9 rerun): attention = R5 shape (768 blocks, 4 qt/wave, single
// staging, rolled loops) + padded LDS (no per-chunk cndmask), dual O chains,
// rcp epilogue. VGPR stays ~64 (no unroll).
// ---------------------------------------------------------------------------
__global__ __launch_bounds__(256) void attn_kernel(
    const float* __restrict__ qkv, float* __restrict__ obuf)
{
    __shared__ uint4 ak1[16 * 32];    //  8.0 KB  k_hi
    __shared__ uint4 ak2p[16 * 33];   //  8.3 KB  k_lo | zero column
    __shared__ uint4 vfh[640];        // 10.0 KB  V_hi frags (+zero pad)
    __shared__ uint4 vfl[640];        // 10.0 KB  V_lo frags (+zero pad)

    const int tid  = threadIdx.x;
    const int lane = tid & 63;
    const int l31  = lane & 31;
    const int hh   = lane >> 5;
    const int wv   = tid >> 6;
    const int head = blockIdx.x & 7;
    const int bt   = blockIdx.x >> 3;

    const size_t rowbase = (size_t)bt * NSEQ * 64 + (size_t)head * 8;
    const float* Qp = qkv + QOFF + rowbase;
    const float* Kp = qkv + KOFF + rowbase;
    const float* Vp = qkv + VOFF + rowbase;

    const uint4 z4 = make_uint4(0, 0, 0, 0);

    #pragma unroll
    for (int kk = 0; kk < 2; ++kk) {
        const int k = tid + kk * 256;
        const float* kr = Kp + (size_t)k * 64;
        float kv[8];
        float4 a = *(const float4*)(kr);
        float4 b = *(const float4*)(kr + 4);
        kv[0] = a.x; kv[1] = a.y; kv[2] = a.z; kv[3] = a.w;
        kv[4] = b.x; kv[5] = b.y; kv[6] = b.z; kv[7] = b.w;
        uint4 hi, lo;
        split_pack8(kv, &hi, &lo);
        ak1[k] = hi;
        ak2p[(k >> 5) * 33 + (k & 31)] = lo;
    }
    if (tid < 16) ak2p[tid * 33 + 32] = z4;

    for (int e = tid; e < 640; e += 256) {
        if (e < 576) {
            int s  = e / 18;
            int r  = e % 18;
            int hv = r / 9;
            int n  = r % 9;
            float vv[8];
            #pragma unroll
            for (int j = 0; j < 8; ++j) {
                int key = 16 * s + ((j < 4) ? (4 * hv + j) : (8 + 4 * hv + (j - 4)));
                vv[j] = (n < 8) ? Vp[(size_t)key * 64 + n] : 1.0f;
            }
            uint4 hi, lo;
            split_pack8(vv, &hi, &lo);
            vfh[e] = hi;
            vfl[e] = lo;
        } else {
            vfh[e] = z4;
            vfl[e] = z4;
        }
    }

    __syncthreads();

    const float C = 0.51012091684045906f;  // log2(e)/sqrt(8)
    const int idx2 = hh ? 32 : l31;        // zero column for hh=1 lanes

    float16v Z16;
    #pragma unroll
    for (int i = 0; i < 16; ++i) Z16[i] = 0.f;

    for (int qt = wv; qt < 16; qt += 4) {
        const float* qp = Qp + (size_t)(qt * 32 + l31) * 64;
        float qv[8];
        {
            float4 a = *(const float4*)(qp);
            float4 b = *(const float4*)(qp + 4);
            qv[0] = a.x * C; qv[1] = a.y * C; qv[2] = a.z * C; qv[3] = a.w * C;
            qv[4] = b.x * C; qv[5] = b.y * C; qv[6] = b.z * C; qv[7] = b.w * C;
        }
        uint4 qhi, qlo;
        split_pack8(qv, &qhi, &qlo);
        const uint4 bq1 = hh ? qlo : qhi;
        const uint4 bq2 = qhi;

        float16v Oa = Z16, Ob = Z16;

        for (int c = 0; c < 16; ++c) {
            const uint4 a1 = ak1[c * 32 + l31];
            const uint4 a2 = ak2p[c * 33 + idx2];
            const int vi0 = (4 * c + hh) * 9;
            const int vi1 = (4 * c + 2 + hh) * 9;
            const uint4 bh0 = vfh[vi0 + l31];
            const uint4 bl0 = vfl[vi0 + l31];
            const uint4 bh1 = vfh[vi1 + l31];
            const uint4 bl1 = vfl[vi1 + l31];

            float16v S;
            S = __builtin_amdgcn_mfma_f32_32x32x16_bf16(as_s8(a1), as_s8(bq1), Z16, 0, 0, 0);
            S = __builtin_amdgcn_mfma_f32_32x32x16_bf16(as_s8(a2), as_s8(bq2), S, 0, 0, 0);

            float pv[16];
            #pragma unroll
            for (int i = 0; i < 16; ++i) pv[i] = fast_exp2(S[i]);

            uint4 ph0, pl0, ph1, pl1;
            split_pack8(&pv[0], &ph0, &pl0);
            split_pack8(&pv[8], &ph1, &pl1);

            Oa = __builtin_amdgcn_mfma_f32_32x32x16_bf16(as_s8(ph0), as_s8(bh0), Oa, 0, 0, 0);
            Ob = __builtin_amdgcn_mfma_f32_32x32x16_bf16(as_s8(ph1), as_s8(bh1), Ob, 0, 0, 0);
            Oa = __builtin_amdgcn_mfma_f32_32x32x16_bf16(as_s8(pl0), as_s8(bh0), Oa, 0, 0, 0);
            Ob = __builtin_amdgcn_mfma_f32_32x32x16_bf16(as_s8(pl1), as_s8(bh1), Ob, 0, 0, 0);
            Oa = __builtin_amdgcn_mfma_f32_32x32x16_bf16(as_s8(ph0), as_s8(bl0), Oa, 0, 0, 0);
            Ob = __builtin_amdgcn_mfma_f32_32x32x16_bf16(as_s8(ph1), as_s8(bl1), Ob, 0, 0, 0);
        }

        #pragma unroll
        for (int r = 0; r < 16; ++r) {
            float ov = Oa[r] + Ob[r];
            float den = __uint_as_float(
                __builtin_amdgcn_ds_swizzle(__float_as_uint(ov), 0x100));
            float o = ov * fast_rcp(den);
            if (l31 < 8) {
                int row = (r & 3) + 8 * (r >> 2) + 4 * hh;
                obuf[rowbase + (size_t)(qt * 32 + row) * 64 + l31] = o;
            }
        }
    }
}

// ---------------------------------------------------------------------------
// Kernel 3 (R8, kept): fused projection through LDS.
// ---------------------------------------------------------------------------
__global__ __launch_bounds__(64) void proj_kernel(
    const float* __restrict__ obuf,
    const uint4* __restrict__ WfH, const uint4* __restrict__ WfL,
    const float* __restrict__ b10, const float* __restrict__ b11,
    float* __restrict__ out)
{
    __shared__ float Ts[32][68];

    const int lane = threadIdx.x;
    const int l31  = lane & 31;
    const int hh   = lane >> 5;
    const size_t row = (size_t)blockIdx.x * 32 + l31;
    const size_t blockrow = (size_t)blockIdx.x * 32;

    float16v accM[2], accC[2];
    #pragma unroll
    for (int t = 0; t < 2; ++t)
        #pragma unroll
        for (int i = 0; i < 16; ++i) { accM[t][i] = 0.f; accC[t][i] = 0.f; }

    #pragma unroll
    for (int c = 0; c < 4; ++c) {
        const float* ap = obuf + row * 64 + c * 16 + hh * 8;
        float av[8];
        {
            float4 a0 = *(const float4*)(ap);
            float4 a1 = *(const float4*)(ap + 4);
            av[0] = a0.x; av[1] = a0.y; av[2] = a0.z; av[3] = a0.w;
            av[4] = a1.x; av[5] = a1.y; av[6] = a1.z; av[7] = a1.w;
        }
        uint4 ahi, alo;
        split_pack8(av, &ahi, &alo);

        #pragma unroll
        for (int t = 0; t < 2; ++t) {
            const int ei = 3072 + c * 128 + hh * 64 + t * 32 + l31;   // W10
            const uint4 bh = WfH[ei];
            const uint4 bl = WfL[ei];
            accM[t] = __builtin_amdgcn_mfma_f32_32x32x16_bf16(
                as_s8(ahi), as_s8(bh), accM[t], 0, 0, 0);
            accC[t] = __builtin_amdgcn_mfma_f32_32x32x16_bf16(
                as_s8(alo), as_s8(bh), accC[t], 0, 0, 0);
            accC[t] = __builtin_amdgcn_mfma_f32_32x32x16_bf16(
                as_s8(ahi), as_s8(bl), accC[t], 0, 0, 0);
        }
    }

    #pragma unroll
    for (int t = 0; t < 2; ++t) {
        const int col = t * 32 + l31;
        const float bias = b10[col];
        #pragma unroll
        for (int r = 0; r < 16; ++r) {
            const int rowC = (r & 3) + 8 * (r >> 2) + 4 * hh;
            Ts[rowC][col] = fmaxf(accM[t][r] + accC[t][r] + bias, 0.f);
        }
    }
    __syncthreads();

    #pragma unroll
    for (int t = 0; t < 2; ++t)
        #pragma unroll
        for (int i = 0; i < 16; ++i) { accM[t][i] = 0.f; accC[t][i] = 0.f; }

    #pragma unroll
    for (int c = 0; c < 4; ++c) {
        const float* ap = &Ts[l31][c * 16 + hh * 8];
        float av[8];
        {
            float4 a0 = *(const float4*)(ap);
            float4 a1 = *(const float4*)(ap + 4);
            av[0] = a0.x; av[1] = a0.y; av[2] = a0.z; av[3] = a0.w;
            av[4] = a1.x; av[5] = a1.y; av[6] = a1.z; av[7] = a1.w;
        }
        uint4 ahi, alo;
        split_pack8(av, &ahi, &alo);

        #pragma unroll
        for (int t = 0; t < 2; ++t) {
            const int ei = 3584 + c * 128 + hh * 64 + t * 32 + l31;   // W11
            const uint4 bh = WfH[ei];
            const uint4 bl = WfL[ei];
            accM[t] = __builtin_amdgcn_mfma_f32_32x32x16_bf16(
                as_s8(ahi), as_s8(bh), accM[t], 0, 0, 0);
            accC[t] = __builtin_amdgcn_mfma_f32_32x32x16_bf16(
                as_s8(alo), as_s8(bh), accC[t], 0, 0, 0);
            accC[t] = __builtin_amdgcn_mfma_f32_32x32x16_bf16(
                as_s8(ahi), as_s8(bl), accC[t], 0, 0, 0);
        }
    }

    #pragma unroll
    for (int t = 0; t < 2; ++t) {
        const int col = t * 32 + l31;
        const float bias = b11[col];
        #pragma unroll
        for (int r = 0; r < 16; ++r) {
            const int rowC = (r & 3) + 8 * (r >> 2) + 4 * hh;
            out[(blockrow + rowC) * 64 + col] = accM[t][r] + accC[t][r] + bias;
        }
    }
}

// ---------------------------------------------------------------------------
extern "C" void kernel_launch(void* const* d_in, const int* in_sizes, int n_in,
                              void* d_out, int out_size, void* d_ws, size_t ws_size,
                              hipStream_t stream)
{
    const float* X   = (const float*)d_in[0];
    const float* STE = (const float*)d_in[1];
    const float* W7  = (const float*)d_in[2];
    const float* b7  = (const float*)d_in[3];
    const float* W8  = (const float*)d_in[4];
    const float* b8  = (const float*)d_in[5];
    const float* W9  = (const float*)d_in[6];
    const float* b9  = (const float*)d_in[7];
    const float* W10 = (const float*)d_in[8];
    const float* b10 = (const float*)d_in[9];
    const float* W11 = (const float*)d_in[10];
    const float* b11 = (const float*)d_in[11];

    float* ws  = (float*)d_ws;   // Q | K | V | O | Wf
    float* out = (float*)d_out;

    uint4* WfH = (uint4*)(ws + WOFF);
    uint4* WfL = WfH + 4096;

    wprep_kernel<<<dim3(16), 256, 0, stream>>>(W7, W8, W9, W10, W11, WfH, WfL);
    qkv_kernel<<<dim3(RTOT / 32, 3), 64, 0, stream>>>(X, STE, WfH, WfL, b7, b8, b9, ws);
    attn_kernel<<<dim3(BT * 8), 256, 0, stream>>>(ws, ws + OOFF);
    proj_kernel<<<dim3(RTOT / 32), 64, 0, stream>>>(ws + OOFF, WfH, WfL, b10, b11, out);
}